// Round 3
// baseline (760.737 us; speedup 1.0000x reference)
//
#include <hip/hip_runtime.h>
#include <cstdint>
#include <cstddef>

#define NNODES 100000
#define DIM 128

// ---------------- small utility kernels ----------------

__global__ void fill_deg(float* __restrict__ deg, int n) {
  int i = blockIdx.x * 256 + threadIdx.x;
  if (i < n) deg[i] = 1.0f;   // "+1.0" self-loop degree
}

__global__ void deg_count(const int* __restrict__ dst, float* __restrict__ deg, int E) {
  int e = blockIdx.x * 256 + threadIdx.x;
  if (e < E) atomicAdd(&deg[dst[e]], 1.0f);
}

// segment sum over f32 rows: 128 threads/edge
__global__ void scatter_sum_f32(const float* __restrict__ x, const int* __restrict__ src,
                                const int* __restrict__ dst, float* __restrict__ sum,
                                float* __restrict__ cnt, int E) {
  int gid = blockIdx.x * 256 + threadIdx.x;
  int e = gid >> 7;
  if (e >= E) return;
  int c = gid & 127;
  int s = src[e], d = dst[e];
  atomicAdd(&sum[(size_t)d * DIM + c], x[(size_t)s * DIM + c]);
  if (c == 0) atomicAdd(&cnt[d], 1.0f);
}

__global__ void finalize_mean(float* __restrict__ sum, const float* __restrict__ cnt, int n) {
  int gid = blockIdx.x * 256 + threadIdx.x;
  int i = gid >> 7;
  if (i >= n) return;
  float c = fmaxf(cnt[i], 1.0f);
  sum[gid] = sum[gid] / c;
}

// x2 = h * (1/deg) + b_gcn  (GCN self-loop term, pre-init before edge scatter)
__global__ void init_self(const float* __restrict__ h, const float* __restrict__ deg,
                          const float* __restrict__ bias, float* __restrict__ x2, int n) {
  int gid = blockIdx.x * 256 + threadIdx.x;
  int i = gid >> 7, c = gid & 127;
  if (i >= n) return;
  x2[gid] = h[gid] * (1.0f / deg[i]) + bias[c];
}

// x2[d] += rsqrt(deg[s]*deg[d]) * h[s], 128 threads/edge
__global__ void gcn_scatter(const float* __restrict__ h, const int* __restrict__ src,
                            const int* __restrict__ dst, const float* __restrict__ deg,
                            float* __restrict__ x2, int E) {
  int gid = blockIdx.x * 256 + threadIdx.x;
  int e = gid >> 7;
  if (e >= E) return;
  int c = gid & 127;
  int s = src[e], d = dst[e];
  float norm = rsqrtf(deg[s] * deg[d]);
  atomicAdd(&x2[(size_t)d * DIM + c], norm * h[(size_t)s * DIM + c]);
}

// ---------------- f32 GEMM: out = act(pre + A[N,128] @ W[128,128] + b) ----------------
// 64-row tile per block, A staged in LDS (pad 132 to vary banks), W read via L1/L2
// (64 KB, hot across all 1563 blocks). 256 threads: thread t computes rows
// rg..rg+7 (rg=(t>>5)*8) x cols c..c+3 (c=(t&31)*4). 32 f32 accs/thread.
// NOTE: `pre` and `out` may alias element-for-element (final stage reads
// x2=d_out and writes d_out) — same thread, read-before-write; no __restrict__.
template<int PRE, int BIAS, int RELU>
__global__ __launch_bounds__(256) void gemm_f32(const float* __restrict__ A,
    const float* __restrict__ W, const float* __restrict__ bias,
    const float* pre, float* out, int nrows)
{
  __shared__ float Al[64 * 132];   // 33 KB
  const int tid = threadIdx.x;
  const int rowblk = blockIdx.x * 64;

  for (int i = tid; i < 64 * 32; i += 256) {
    int r = i >> 5, c4 = (i & 31) << 2;
    int gr = rowblk + r;
    float4 v = {0.f, 0.f, 0.f, 0.f};
    if (gr < nrows) v = *(const float4*)(A + (size_t)gr * DIM + c4);
    *(float4*)&Al[r * 132 + c4] = v;
  }
  __syncthreads();

  const int rg = (tid >> 5) << 3;   // row group start within tile
  const int c  = (tid & 31) << 2;   // 4 output cols

  float acc[8][4];
#pragma unroll
  for (int i = 0; i < 8; ++i)
#pragma unroll
    for (int j = 0; j < 4; ++j) acc[i][j] = 0.f;

#pragma unroll 4
  for (int k = 0; k < DIM; ++k) {
    float4 w = *(const float4*)(W + k * DIM + c);
#pragma unroll
    for (int i = 0; i < 8; ++i) {
      float a = Al[(rg + i) * 132 + k];
      acc[i][0] = fmaf(a, w.x, acc[i][0]);
      acc[i][1] = fmaf(a, w.y, acc[i][1]);
      acc[i][2] = fmaf(a, w.z, acc[i][2]);
      acc[i][3] = fmaf(a, w.w, acc[i][3]);
    }
  }

  float4 bv = {0.f, 0.f, 0.f, 0.f};
  if (BIAS) bv = *(const float4*)(bias + c);
#pragma unroll
  for (int i = 0; i < 8; ++i) {
    int gr = rowblk + rg + i;
    if (gr < nrows) {
      size_t off = (size_t)gr * DIM + c;
      float4 p = {0.f, 0.f, 0.f, 0.f};
      if (PRE) p = *(const float4*)(pre + off);
      float4 o;
      o.x = acc[i][0] + bv.x + p.x;
      o.y = acc[i][1] + bv.y + p.y;
      o.z = acc[i][2] + bv.z + p.z;
      o.w = acc[i][3] + bv.w + p.w;
      if (RELU) {
        o.x = fmaxf(o.x, 0.f); o.y = fmaxf(o.y, 0.f);
        o.z = fmaxf(o.z, 0.f); o.w = fmaxf(o.w, 0.f);
      }
      *(float4*)(out + off) = o;
    }
  }
}

extern "C" void kernel_launch(void* const* d_in, const int* in_sizes, int n_in,
                              void* d_out, int out_size, void* d_ws, size_t ws_size,
                              hipStream_t stream) {
  const float* emb = (const float*)d_in[0];
  const float* Wd  = (const float*)d_in[1];
  const float* bd  = (const float*)d_in[2];
  const float* Wg  = (const float*)d_in[3];
  const float* bg  = (const float*)d_in[4];
  const float* Wu  = (const float*)d_in[5];
  const float* bu  = (const float*)d_in[6];
  const int* d2u = (const int*)d_in[7];
  const int* sle = (const int*)d_in[8];
  const int* u2d = (const int*)d_in[9];
  const int E1 = in_sizes[7] / 2;   // 100000
  const int E2 = in_sizes[8] / 2;   // 600000
  const int E3 = in_sizes[9] / 2;   // 100000
  const int N  = NNODES;
  const size_t nd = (size_t)N * DIM;

  // ws: bufA [N*D f32] | cnt [N] | deg [N]   (~52 MB). bufB = d_out (ping-pong).
  float* bufA = (float*)d_ws;
  float* cnt  = bufA + nd;
  float* deg  = cnt + N;
  float* bufB = (float*)d_out;

  const int gemm_blocks = (N + 63) / 64;
  const int ndb = (int)(nd / 256);   // nd = 12.8M, divisible by 256

  // ---- stage A: down2up segment-mean, then x1 = relu(emb + agg@Wd + bd) ----
  (void)hipMemsetAsync(bufA, 0, nd * sizeof(float), stream);
  (void)hipMemsetAsync(cnt, 0, (size_t)N * sizeof(float), stream);
  scatter_sum_f32<<<(int)(((size_t)E1 * 128) / 256), 256, 0, stream>>>(emb, d2u, d2u + E1, bufA, cnt, E1);
  finalize_mean<<<ndb, 256, 0, stream>>>(bufA, cnt, N);
  gemm_f32<1, 1, 1><<<gemm_blocks, 256, 0, stream>>>(bufA, Wd, bd, emb, bufB, N);   // x1 -> d_out

  // ---- stage B: GCN ----
  fill_deg<<<(N + 255) / 256, 256, 0, stream>>>(deg, N);
  deg_count<<<(E2 + 255) / 256, 256, 0, stream>>>(sle + E2, deg, E2);
  gemm_f32<0, 0, 0><<<gemm_blocks, 256, 0, stream>>>(bufB, Wg, nullptr, nullptr, bufA, N);  // h -> ws
  init_self<<<ndb, 256, 0, stream>>>(bufA, deg, bg, bufB, N);                                // x2 = h/deg + bg
  gcn_scatter<<<(int)(((size_t)E2 * 128) / 256), 256, 0, stream>>>(bufA, sle, sle + E2, deg, bufB, E2);

  // ---- stage C: up2down segment-mean + final transform ----
  (void)hipMemsetAsync(bufA, 0, nd * sizeof(float), stream);
  (void)hipMemsetAsync(cnt, 0, (size_t)N * sizeof(float), stream);
  scatter_sum_f32<<<(int)(((size_t)E3 * 128) / 256), 256, 0, stream>>>(bufB, u2d, u2d + E3, bufA, cnt, E3);
  finalize_mean<<<ndb, 256, 0, stream>>>(bufA, cnt, N);
  // out = relu(x2 + agg2@Wu + bu); pre (=x2=bufB=d_out) aliases out element-wise — safe.
  gemm_f32<1, 1, 1><<<gemm_blocks, 256, 0, stream>>>(bufA, Wu, bu, bufB, bufB, N);
}

// Round 4
// 493.301 us; speedup vs baseline: 1.5421x; 1.5421x over previous
//
#include <hip/hip_runtime.h>
#include <cstdint>
#include <cstddef>

#define NNODES 100000
#define DIM 128

// =================== CSR build: count -> scan -> fill ===================

__global__ void count_dst(const int* __restrict__ dst, int* __restrict__ cnt, int E) {
  int e = blockIdx.x * 256 + threadIdx.x;
  if (e < E) atomicAdd(&cnt[dst[e]], 1);
}

// block-level exclusive scan over 1024-element chunks; bsum[b] = chunk total
__global__ void scan_blocks(const int* __restrict__ in, int* __restrict__ out,
                            int* __restrict__ bsum, int n) {
  __shared__ int wsum[4];
  const int tid = threadIdx.x;
  const int base = blockIdx.x * 1024 + tid * 4;
  int v0 = 0, v1 = 0, v2 = 0, v3 = 0;
  if (base + 0 < n) v0 = in[base + 0];
  if (base + 1 < n) v1 = in[base + 1];
  if (base + 2 < n) v2 = in[base + 2];
  if (base + 3 < n) v3 = in[base + 3];
  const int tsum = v0 + v1 + v2 + v3;
  const int lane = tid & 63, wid = tid >> 6;
  int x = tsum;
  for (int off = 1; off < 64; off <<= 1) {
    int y = __shfl_up(x, off, 64);
    if (lane >= off) x += y;
  }
  if (lane == 63) wsum[wid] = x;
  __syncthreads();
  int woff = 0;
  for (int w = 0; w < wid; ++w) woff += wsum[w];
  const int excl = woff + x - tsum;
  if (base + 0 < n) out[base + 0] = excl;
  if (base + 1 < n) out[base + 1] = excl + v0;
  if (base + 2 < n) out[base + 2] = excl + v0 + v1;
  if (base + 3 < n) out[base + 3] = excl + v0 + v1 + v2;
  if (tid == 255) bsum[blockIdx.x] = woff + x;
}

// single-block scan of up to 1024 block sums; bsum becomes exclusive offsets
__global__ void scan_top(int* __restrict__ bsum, int nb) {
  __shared__ int tmp[1024];
  const int tid = threadIdx.x;
  for (int i = tid; i < 1024; i += 256) tmp[i] = (i < nb) ? bsum[i] : 0;
  __syncthreads();
  for (int off = 1; off < 1024; off <<= 1) {
    int vals[4];
#pragma unroll
    for (int j = 0; j < 4; ++j) { int i = tid + j * 256; vals[j] = (i >= off) ? tmp[i - off] : 0; }
    __syncthreads();
#pragma unroll
    for (int j = 0; j < 4; ++j) { int i = tid + j * 256; tmp[i] += vals[j]; }
    __syncthreads();
  }
  for (int i = tid; i < nb; i += 256) {
    int orig = bsum[i];
    bsum[i] = tmp[i] - orig;   // exclusive
  }
}

__global__ void scan_add(int* __restrict__ out, const int* __restrict__ bsum, int n) {
  const int b = blockIdx.x;
  const int off = bsum[b];
  const int base = b * 1024 + threadIdx.x * 4;
#pragma unroll
  for (int j = 0; j < 4; ++j)
    if (base + j < n) out[base + j] += off;
}

__global__ void fill_csr(const int* __restrict__ src, const int* __restrict__ dst,
                         const int* __restrict__ rs, int* __restrict__ fill,
                         int* __restrict__ eidx, int E) {
  int e = blockIdx.x * 256 + threadIdx.x;
  if (e >= E) return;
  int d = dst[e];
  int p = rs[d] + atomicAdd(&fill[d], 1);
  eidx[p] = src[e];
}

__global__ void make_rnorm(const int* __restrict__ cnt, float* __restrict__ rnorm, int n) {
  int i = blockIdx.x * 256 + threadIdx.x;
  if (i < n) rnorm[i] = rsqrtf((float)cnt[i] + 1.0f);
}

// =================== gathers (32 threads / node, float4 cols) ===================

// out[i] = mean over incoming edges of x[src]
__global__ void gather_mean(const float* __restrict__ x, const int* __restrict__ rs,
                            const int* __restrict__ cnt, const int* __restrict__ eidx,
                            float* __restrict__ out, int n) {
  int gid = blockIdx.x * 256 + threadIdx.x;
  int i = gid >> 5;
  if (i >= n) return;
  int c = (gid & 31) << 2;
  int start = rs[i], m = cnt[i];
  float4 acc = {0.f, 0.f, 0.f, 0.f};
  for (int j = 0; j < m; ++j) {
    int s = eidx[start + j];
    float4 v = *(const float4*)(x + (size_t)s * DIM + c);
    acc.x += v.x; acc.y += v.y; acc.z += v.z; acc.w += v.w;
  }
  float inv = 1.0f / fmaxf((float)m, 1.0f);
  acc.x *= inv; acc.y *= inv; acc.z *= inv; acc.w *= inv;
  *(float4*)(out + (size_t)i * DIM + c) = acc;
}

// x2[i] = rnorm[i] * sum_e rnorm[s]*h[s] + h[i]*rnorm[i]^2 + bias
__global__ void gather_gcn(const float* __restrict__ h, const int* __restrict__ rs,
                           const int* __restrict__ cnt, const int* __restrict__ eidx,
                           const float* __restrict__ rnorm, const float* __restrict__ bias,
                           float* __restrict__ out, int n) {
  int gid = blockIdx.x * 256 + threadIdx.x;
  int i = gid >> 5;
  if (i >= n) return;
  int c = (gid & 31) << 2;
  int start = rs[i], m = cnt[i];
  float4 acc = {0.f, 0.f, 0.f, 0.f};
  for (int j = 0; j < m; ++j) {
    int s = eidx[start + j];
    float rn = rnorm[s];
    float4 v = *(const float4*)(h + (size_t)s * DIM + c);
    acc.x = fmaf(rn, v.x, acc.x);
    acc.y = fmaf(rn, v.y, acc.y);
    acc.z = fmaf(rn, v.z, acc.z);
    acc.w = fmaf(rn, v.w, acc.w);
  }
  float ri = rnorm[i];
  float invd = ri * ri;
  float4 hv = *(const float4*)(h + (size_t)i * DIM + c);
  float4 bv = *(const float4*)(bias + c);
  float4 o;
  o.x = fmaf(ri, acc.x, fmaf(invd, hv.x, bv.x));
  o.y = fmaf(ri, acc.y, fmaf(invd, hv.y, bv.y));
  o.z = fmaf(ri, acc.z, fmaf(invd, hv.z, bv.z));
  o.w = fmaf(ri, acc.w, fmaf(invd, hv.w, bv.w));
  *(float4*)(out + (size_t)i * DIM + c) = o;
}

// =================== f32 GEMM: out = act(pre + A @ W + b) ===================
// 64-row tile/block; A in LDS (pad 132); W via L1/L2. Thread t: rows (t>>5)*8..+7,
// cols (t&31)*4..+3. `pre`/`out` may alias element-for-element (same thread) — no restrict.
template<int PRE, int BIAS, int RELU>
__global__ __launch_bounds__(256) void gemm_f32(const float* __restrict__ A,
    const float* __restrict__ W, const float* __restrict__ bias,
    const float* pre, float* out, int nrows)
{
  __shared__ float Al[64 * 132];
  const int tid = threadIdx.x;
  const int rowblk = blockIdx.x * 64;

  for (int i = tid; i < 64 * 32; i += 256) {
    int r = i >> 5, c4 = (i & 31) << 2;
    int gr = rowblk + r;
    float4 v = {0.f, 0.f, 0.f, 0.f};
    if (gr < nrows) v = *(const float4*)(A + (size_t)gr * DIM + c4);
    *(float4*)&Al[r * 132 + c4] = v;
  }
  __syncthreads();

  const int rg = (tid >> 5) << 3;
  const int c  = (tid & 31) << 2;

  float acc[8][4];
#pragma unroll
  for (int i = 0; i < 8; ++i)
#pragma unroll
    for (int j = 0; j < 4; ++j) acc[i][j] = 0.f;

#pragma unroll 4
  for (int k = 0; k < DIM; ++k) {
    float4 w = *(const float4*)(W + k * DIM + c);
#pragma unroll
    for (int i = 0; i < 8; ++i) {
      float a = Al[(rg + i) * 132 + k];
      acc[i][0] = fmaf(a, w.x, acc[i][0]);
      acc[i][1] = fmaf(a, w.y, acc[i][1]);
      acc[i][2] = fmaf(a, w.z, acc[i][2]);
      acc[i][3] = fmaf(a, w.w, acc[i][3]);
    }
  }

  float4 bv = {0.f, 0.f, 0.f, 0.f};
  if (BIAS) bv = *(const float4*)(bias + c);
#pragma unroll
  for (int i = 0; i < 8; ++i) {
    int gr = rowblk + rg + i;
    if (gr < nrows) {
      size_t off = (size_t)gr * DIM + c;
      float4 p = {0.f, 0.f, 0.f, 0.f};
      if (PRE) p = *(const float4*)(pre + off);
      float4 o;
      o.x = acc[i][0] + bv.x + p.x;
      o.y = acc[i][1] + bv.y + p.y;
      o.z = acc[i][2] + bv.z + p.z;
      o.w = acc[i][3] + bv.w + p.w;
      if (RELU) {
        o.x = fmaxf(o.x, 0.f); o.y = fmaxf(o.y, 0.f);
        o.z = fmaxf(o.z, 0.f); o.w = fmaxf(o.w, 0.f);
      }
      *(float4*)(out + off) = o;
    }
  }
}

// =================== host ===================

extern "C" void kernel_launch(void* const* d_in, const int* in_sizes, int n_in,
                              void* d_out, int out_size, void* d_ws, size_t ws_size,
                              hipStream_t stream) {
  const float* emb = (const float*)d_in[0];
  const float* Wd  = (const float*)d_in[1];
  const float* bd  = (const float*)d_in[2];
  const float* Wg  = (const float*)d_in[3];
  const float* bg  = (const float*)d_in[4];
  const float* Wu  = (const float*)d_in[5];
  const float* bu  = (const float*)d_in[6];
  const int* d2u = (const int*)d_in[7];
  const int* sle = (const int*)d_in[8];
  const int* u2d = (const int*)d_in[9];
  const int E1 = in_sizes[7] / 2;   // 100000
  const int E2 = in_sizes[8] / 2;   // 600000
  const int E3 = in_sizes[9] / 2;   // 100000
  const int N  = NNODES;
  const size_t nd = (size_t)N * DIM;

  // ws layout: bufA[nd f32] | cntA,fillA,cntB,fillB,cntC,fillC [6N int] |
  //            rsA,rsB,rsC [3N int] | eidxA[E1] eidxB[E2] eidxC[E3] | rnorm[N f32] |
  //            bsumA,bsumB,bsumC [3*1024 int]   (~58.7 MB total)
  float* bufA = (float*)d_ws;
  int* cntA  = (int*)(bufA + nd);
  int* fillA = cntA + N;
  int* cntB  = fillA + N;
  int* fillB = cntB + N;
  int* cntC  = fillB + N;
  int* fillC = cntC + N;
  int* rsA   = fillC + N;
  int* rsB   = rsA + N;
  int* rsC   = rsB + N;
  int* eidxA = rsC + N;
  int* eidxB = eidxA + E1;
  int* eidxC = eidxB + E2;
  float* rnorm = (float*)(eidxC + E3);
  int* bsumA = (int*)(rnorm + N);
  int* bsumB = bsumA + 1024;
  int* bsumC = bsumB + 1024;
  float* bufB = (float*)d_out;

  const int gemm_blocks = (N + 63) / 64;
  const int nscan = (N + 1023) / 1024;            // 98
  const int ngather = (N * 32 + 255) / 256;       // 12500

  // ---- build all three CSRs ----
  (void)hipMemsetAsync(cntA, 0, (size_t)6 * N * sizeof(int), stream);
  count_dst<<<(E1 + 255) / 256, 256, 0, stream>>>(d2u + E1, cntA, E1);
  count_dst<<<(E2 + 255) / 256, 256, 0, stream>>>(sle + E2, cntB, E2);
  count_dst<<<(E3 + 255) / 256, 256, 0, stream>>>(u2d + E3, cntC, E3);
  make_rnorm<<<(N + 255) / 256, 256, 0, stream>>>(cntB, rnorm, N);
  scan_blocks<<<nscan, 256, 0, stream>>>(cntA, rsA, bsumA, N);
  scan_blocks<<<nscan, 256, 0, stream>>>(cntB, rsB, bsumB, N);
  scan_blocks<<<nscan, 256, 0, stream>>>(cntC, rsC, bsumC, N);
  scan_top<<<1, 256, 0, stream>>>(bsumA, nscan);
  scan_top<<<1, 256, 0, stream>>>(bsumB, nscan);
  scan_top<<<1, 256, 0, stream>>>(bsumC, nscan);
  scan_add<<<nscan, 256, 0, stream>>>(rsA, bsumA, N);
  scan_add<<<nscan, 256, 0, stream>>>(rsB, bsumB, N);
  scan_add<<<nscan, 256, 0, stream>>>(rsC, bsumC, N);
  fill_csr<<<(E1 + 255) / 256, 256, 0, stream>>>(d2u, d2u + E1, rsA, fillA, eidxA, E1);
  fill_csr<<<(E2 + 255) / 256, 256, 0, stream>>>(sle, sle + E2, rsB, fillB, eidxB, E2);
  fill_csr<<<(E3 + 255) / 256, 256, 0, stream>>>(u2d, u2d + E3, rsC, fillC, eidxC, E3);

  // ---- stage A: agg1 = segment_mean(emb) ; x1 = relu(emb + agg1@Wd + bd) ----
  gather_mean<<<ngather, 256, 0, stream>>>(emb, rsA, cntA, eidxA, bufA, N);
  gemm_f32<1, 1, 1><<<gemm_blocks, 256, 0, stream>>>(bufA, Wd, bd, emb, bufB, N);   // x1 -> d_out

  // ---- stage B: h = x1@Wg ; x2 = gcn(h) ----
  gemm_f32<0, 0, 0><<<gemm_blocks, 256, 0, stream>>>(bufB, Wg, nullptr, nullptr, bufA, N);  // h -> ws
  gather_gcn<<<ngather, 256, 0, stream>>>(bufA, rsB, cntB, eidxB, rnorm, bg, bufB, N);       // x2 -> d_out

  // ---- stage C: agg2 = segment_mean(x2) ; out = relu(x2 + agg2@Wu + bu) ----
  gather_mean<<<ngather, 256, 0, stream>>>(bufB, rsC, cntC, eidxC, bufA, N);
  gemm_f32<1, 1, 1><<<gemm_blocks, 256, 0, stream>>>(bufA, Wu, bu, bufB, bufB, N);
}

// Round 5
// 492.322 us; speedup vs baseline: 1.5452x; 1.0020x over previous
//
#include <hip/hip_runtime.h>
#include <cstdint>
#include <cstddef>

#define NNODES 100000
#define DIM 128

// =================== CSR build: count -> scan -> fill ===================

__global__ void count_dst(const int* __restrict__ dst, int* __restrict__ cnt, int E) {
  int e = blockIdx.x * 256 + threadIdx.x;
  if (e < E) atomicAdd(&cnt[dst[e]], 1);
}

// block-level exclusive scan over 1024-element chunks; bsum[b] = chunk total
__global__ void scan_blocks(const int* __restrict__ in, int* __restrict__ out,
                            int* __restrict__ bsum, int n) {
  __shared__ int wsum[4];
  const int tid = threadIdx.x;
  const int base = blockIdx.x * 1024 + tid * 4;
  int v0 = 0, v1 = 0, v2 = 0, v3 = 0;
  if (base + 0 < n) v0 = in[base + 0];
  if (base + 1 < n) v1 = in[base + 1];
  if (base + 2 < n) v2 = in[base + 2];
  if (base + 3 < n) v3 = in[base + 3];
  const int tsum = v0 + v1 + v2 + v3;
  const int lane = tid & 63, wid = tid >> 6;
  int x = tsum;
  for (int off = 1; off < 64; off <<= 1) {
    int y = __shfl_up(x, off, 64);
    if (lane >= off) x += y;
  }
  if (lane == 63) wsum[wid] = x;
  __syncthreads();
  int woff = 0;
  for (int w = 0; w < wid; ++w) woff += wsum[w];
  const int excl = woff + x - tsum;
  if (base + 0 < n) out[base + 0] = excl;
  if (base + 1 < n) out[base + 1] = excl + v0;
  if (base + 2 < n) out[base + 2] = excl + v0 + v1;
  if (base + 3 < n) out[base + 3] = excl + v0 + v1 + v2;
  if (tid == 255) bsum[blockIdx.x] = woff + x;
}

// single-block scan of up to 1024 block sums; bsum becomes exclusive offsets
__global__ void scan_top(int* __restrict__ bsum, int nb) {
  __shared__ int tmp[1024];
  const int tid = threadIdx.x;
  for (int i = tid; i < 1024; i += 256) tmp[i] = (i < nb) ? bsum[i] : 0;
  __syncthreads();
  for (int off = 1; off < 1024; off <<= 1) {
    int vals[4];
#pragma unroll
    for (int j = 0; j < 4; ++j) { int i = tid + j * 256; vals[j] = (i >= off) ? tmp[i - off] : 0; }
    __syncthreads();
#pragma unroll
    for (int j = 0; j < 4; ++j) { int i = tid + j * 256; tmp[i] += vals[j]; }
    __syncthreads();
  }
  for (int i = tid; i < nb; i += 256) {
    int orig = bsum[i];
    bsum[i] = tmp[i] - orig;   // exclusive
  }
}

__global__ void scan_add(int* __restrict__ out, const int* __restrict__ bsum, int n) {
  const int b = blockIdx.x;
  const int off = bsum[b];
  const int base = b * 1024 + threadIdx.x * 4;
#pragma unroll
  for (int j = 0; j < 4; ++j)
    if (base + j < n) out[base + j] += off;
}

__global__ void fill_csr(const int* __restrict__ src, const int* __restrict__ dst,
                         const int* __restrict__ rs, int* __restrict__ fill,
                         int* __restrict__ eidx, int E) {
  int e = blockIdx.x * 256 + threadIdx.x;
  if (e >= E) return;
  int d = dst[e];
  int p = rs[d] + atomicAdd(&fill[d], 1);
  eidx[p] = src[e];
}

__global__ void make_rnorm(const int* __restrict__ cnt, float* __restrict__ rnorm, int n) {
  int i = blockIdx.x * 256 + threadIdx.x;
  if (i < n) rnorm[i] = rsqrtf((float)cnt[i] + 1.0f);
}

// =================== gathers (32 threads / node, float4 cols) ===================

// out[i] = mean over incoming edges of x[src]
__global__ void gather_mean(const float* __restrict__ x, const int* __restrict__ rs,
                            const int* __restrict__ cnt, const int* __restrict__ eidx,
                            float* __restrict__ out, int n) {
  int gid = blockIdx.x * 256 + threadIdx.x;
  int i = gid >> 5;
  if (i >= n) return;
  int c = (gid & 31) << 2;
  int start = rs[i], m = cnt[i];
  float4 acc = {0.f, 0.f, 0.f, 0.f};
  for (int j = 0; j < m; ++j) {
    int s = eidx[start + j];
    float4 v = *(const float4*)(x + (size_t)s * DIM + c);
    acc.x += v.x; acc.y += v.y; acc.z += v.z; acc.w += v.w;
  }
  float inv = 1.0f / fmaxf((float)m, 1.0f);
  acc.x *= inv; acc.y *= inv; acc.z *= inv; acc.w *= inv;
  *(float4*)(out + (size_t)i * DIM + c) = acc;
}

// x2[i] = rnorm[i] * sum_e rnorm[s]*h[s] + h[i]*rnorm[i]^2 + bias
__global__ void gather_gcn(const float* __restrict__ h, const int* __restrict__ rs,
                           const int* __restrict__ cnt, const int* __restrict__ eidx,
                           const float* __restrict__ rnorm, const float* __restrict__ bias,
                           float* __restrict__ out, int n) {
  int gid = blockIdx.x * 256 + threadIdx.x;
  int i = gid >> 5;
  if (i >= n) return;
  int c = (gid & 31) << 2;
  int start = rs[i], m = cnt[i];
  float4 acc = {0.f, 0.f, 0.f, 0.f};
  for (int j = 0; j < m; ++j) {
    int s = eidx[start + j];
    float rn = rnorm[s];
    float4 v = *(const float4*)(h + (size_t)s * DIM + c);
    acc.x = fmaf(rn, v.x, acc.x);
    acc.y = fmaf(rn, v.y, acc.y);
    acc.z = fmaf(rn, v.z, acc.z);
    acc.w = fmaf(rn, v.w, acc.w);
  }
  float ri = rnorm[i];
  float invd = ri * ri;
  float4 hv = *(const float4*)(h + (size_t)i * DIM + c);
  float4 bv = *(const float4*)(bias + c);
  float4 o;
  o.x = fmaf(ri, acc.x, fmaf(invd, hv.x, bv.x));
  o.y = fmaf(ri, acc.y, fmaf(invd, hv.y, bv.y));
  o.z = fmaf(ri, acc.z, fmaf(invd, hv.z, bv.z));
  o.w = fmaf(ri, acc.w, fmaf(invd, hv.w, bv.w));
  *(float4*)(out + (size_t)i * DIM + c) = o;
}

// =================== f32 GEMM: out = act(pre + A @ W + b) ===================
// 64-row tile/block; A in LDS (pad 132, b128-aligned rows); W via L1/L2.
// Thread t: rows (t>>5)*8..+7, cols (t&31)*4..+3. k-loop steps by 4 so A-row
// chunks load as ds_read_b128 (broadcast across lanes, conflict-free) — the
// round-4 version used scalar ds_read_b32 and was LDS-pipe-bound (74 us).
// `pre`/`out` may alias element-for-element (same thread) — no restrict.
template<int PRE, int BIAS, int RELU>
__global__ __launch_bounds__(256) void gemm_f32(const float* __restrict__ A,
    const float* __restrict__ W, const float* __restrict__ bias,
    const float* pre, float* out, int nrows)
{
  __shared__ float Al[64 * 132];
  const int tid = threadIdx.x;
  const int rowblk = blockIdx.x * 64;

  for (int i = tid; i < 64 * 32; i += 256) {
    int r = i >> 5, c4 = (i & 31) << 2;
    int gr = rowblk + r;
    float4 v = {0.f, 0.f, 0.f, 0.f};
    if (gr < nrows) v = *(const float4*)(A + (size_t)gr * DIM + c4);
    *(float4*)&Al[r * 132 + c4] = v;
  }
  __syncthreads();

  const int rg = (tid >> 5) << 3;
  const int c  = (tid & 31) << 2;

  float acc[8][4];
#pragma unroll
  for (int i = 0; i < 8; ++i)
#pragma unroll
    for (int j = 0; j < 4; ++j) acc[i][j] = 0.f;

  for (int k = 0; k < DIM; k += 4) {
    float4 a[8];
#pragma unroll
    for (int i = 0; i < 8; ++i) a[i] = *(const float4*)&Al[(rg + i) * 132 + k];
    float4 w[4];
#pragma unroll
    for (int kk = 0; kk < 4; ++kk) w[kk] = *(const float4*)(W + (k + kk) * DIM + c);
#pragma unroll
    for (int i = 0; i < 8; ++i) {
      const float* av = (const float*)&a[i];
#pragma unroll
      for (int kk = 0; kk < 4; ++kk) {
        acc[i][0] = fmaf(av[kk], w[kk].x, acc[i][0]);
        acc[i][1] = fmaf(av[kk], w[kk].y, acc[i][1]);
        acc[i][2] = fmaf(av[kk], w[kk].z, acc[i][2]);
        acc[i][3] = fmaf(av[kk], w[kk].w, acc[i][3]);
      }
    }
  }

  float4 bv = {0.f, 0.f, 0.f, 0.f};
  if (BIAS) bv = *(const float4*)(bias + c);
#pragma unroll
  for (int i = 0; i < 8; ++i) {
    int gr = rowblk + rg + i;
    if (gr < nrows) {
      size_t off = (size_t)gr * DIM + c;
      float4 p = {0.f, 0.f, 0.f, 0.f};
      if (PRE) p = *(const float4*)(pre + off);
      float4 o;
      o.x = acc[i][0] + bv.x + p.x;
      o.y = acc[i][1] + bv.y + p.y;
      o.z = acc[i][2] + bv.z + p.z;
      o.w = acc[i][3] + bv.w + p.w;
      if (RELU) {
        o.x = fmaxf(o.x, 0.f); o.y = fmaxf(o.y, 0.f);
        o.z = fmaxf(o.z, 0.f); o.w = fmaxf(o.w, 0.f);
      }
      *(float4*)(out + off) = o;
    }
  }
}

// =================== host ===================

extern "C" void kernel_launch(void* const* d_in, const int* in_sizes, int n_in,
                              void* d_out, int out_size, void* d_ws, size_t ws_size,
                              hipStream_t stream) {
  const float* emb = (const float*)d_in[0];
  const float* Wd  = (const float*)d_in[1];
  const float* bd  = (const float*)d_in[2];
  const float* Wg  = (const float*)d_in[3];
  const float* bg  = (const float*)d_in[4];
  const float* Wu  = (const float*)d_in[5];
  const float* bu  = (const float*)d_in[6];
  const int* d2u = (const int*)d_in[7];
  const int* sle = (const int*)d_in[8];
  const int* u2d = (const int*)d_in[9];
  const int E1 = in_sizes[7] / 2;   // 100000
  const int E2 = in_sizes[8] / 2;   // 600000
  const int E3 = in_sizes[9] / 2;   // 100000
  const int N  = NNODES;
  const size_t nd = (size_t)N * DIM;

  // ws layout: bufA[nd f32] | cntA,fillA,cntB,fillB,cntC,fillC [6N int] |
  //            rsA,rsB,rsC [3N int] | eidxA[E1] eidxB[E2] eidxC[E3] | rnorm[N f32] |
  //            bsumA,bsumB,bsumC [3*1024 int]   (~58.7 MB total)
  float* bufA = (float*)d_ws;
  int* cntA  = (int*)(bufA + nd);
  int* fillA = cntA + N;
  int* cntB  = fillA + N;
  int* fillB = cntB + N;
  int* cntC  = fillB + N;
  int* fillC = cntC + N;
  int* rsA   = fillC + N;
  int* rsB   = rsA + N;
  int* rsC   = rsB + N;
  int* eidxA = rsC + N;
  int* eidxB = eidxA + E1;
  int* eidxC = eidxB + E2;
  float* rnorm = (float*)(eidxC + E3);
  int* bsumA = (int*)(rnorm + N);
  int* bsumB = bsumA + 1024;
  int* bsumC = bsumB + 1024;
  float* bufB = (float*)d_out;

  const int gemm_blocks = (N + 63) / 64;
  const int nscan = (N + 1023) / 1024;            // 98
  const int ngather = (N * 32 + 255) / 256;       // 12500

  // ---- build all three CSRs ----
  (void)hipMemsetAsync(cntA, 0, (size_t)6 * N * sizeof(int), stream);
  count_dst<<<(E1 + 255) / 256, 256, 0, stream>>>(d2u + E1, cntA, E1);
  count_dst<<<(E2 + 255) / 256, 256, 0, stream>>>(sle + E2, cntB, E2);
  count_dst<<<(E3 + 255) / 256, 256, 0, stream>>>(u2d + E3, cntC, E3);
  make_rnorm<<<(N + 255) / 256, 256, 0, stream>>>(cntB, rnorm, N);
  scan_blocks<<<nscan, 256, 0, stream>>>(cntA, rsA, bsumA, N);
  scan_blocks<<<nscan, 256, 0, stream>>>(cntB, rsB, bsumB, N);
  scan_blocks<<<nscan, 256, 0, stream>>>(cntC, rsC, bsumC, N);
  scan_top<<<1, 256, 0, stream>>>(bsumA, nscan);
  scan_top<<<1, 256, 0, stream>>>(bsumB, nscan);
  scan_top<<<1, 256, 0, stream>>>(bsumC, nscan);
  scan_add<<<nscan, 256, 0, stream>>>(rsA, bsumA, N);
  scan_add<<<nscan, 256, 0, stream>>>(rsB, bsumB, N);
  scan_add<<<nscan, 256, 0, stream>>>(rsC, bsumC, N);
  fill_csr<<<(E1 + 255) / 256, 256, 0, stream>>>(d2u, d2u + E1, rsA, fillA, eidxA, E1);
  fill_csr<<<(E2 + 255) / 256, 256, 0, stream>>>(sle, sle + E2, rsB, fillB, eidxB, E2);
  fill_csr<<<(E3 + 255) / 256, 256, 0, stream>>>(u2d, u2d + E3, rsC, fillC, eidxC, E3);

  // ---- stage A: agg1 = segment_mean(emb) ; x1 = relu(emb + agg1@Wd + bd) ----
  gather_mean<<<ngather, 256, 0, stream>>>(emb, rsA, cntA, eidxA, bufA, N);
  gemm_f32<1, 1, 1><<<gemm_blocks, 256, 0, stream>>>(bufA, Wd, bd, emb, bufB, N);   // x1 -> d_out

  // ---- stage B: h = x1@Wg ; x2 = gcn(h) ----
  gemm_f32<0, 0, 0><<<gemm_blocks, 256, 0, stream>>>(bufB, Wg, nullptr, nullptr, bufA, N);  // h -> ws
  gather_gcn<<<ngather, 256, 0, stream>>>(bufA, rsB, cntB, eidxB, rnorm, bg, bufB, N);       // x2 -> d_out

  // ---- stage C: agg2 = segment_mean(x2) ; out = relu(x2 + agg2@Wu + bu) ----
  gather_mean<<<ngather, 256, 0, stream>>>(bufB, rsC, cntC, eidxC, bufA, N);
  gemm_f32<1, 1, 1><<<gemm_blocks, 256, 0, stream>>>(bufA, Wu, bu, bufB, bufB, N);
}